// Round 10
// baseline (3198.616 us; speedup 1.0000x reference)
//
#include <hip/hip_runtime.h>

// Neural HMM forward-algorithm NLL.  K=128, V=50257, D=H=128, B=64, T=2048.
//
// Associative scan over t: alpha_t = alpha_{t-1} M_t  (M_t = A diag(e_t)).
// NS segments x 64 batches independent chains, each propagating a 128x128
// matrix Q <- diag(e_t) A^T Q via MX-FP8 MFMA (mfma_scale 16x16x128).
// r9 measured: NSEG=32 -> 2 waves/SIMD, MfmaUtil 46% (= predicted pipe share
// exactly). This round: NSEG=64 -> 4 waves/SIMD + pk-vectorized epilogue.
//
//  K1 k_emis : E128[v][k] = bf16(128*exp(tag_k . word_v + bias_v)) + partial Z
//  K2 k_trans: A2 (Z-folded, fb), A2p = 128*softmax rows, piZ (fb),
//              piPlain = softmax(init), Zinv[j] = V/Z_j
//  K3 k_scan<NS> : per chain: Q init I*128 (fp8), TT/NS steps of
//              Qstored <- 128 * diag(E*V/Z) A^T Qtrue (stored = true*128;
//              SA=SB=2^-7 cancel the two x128 of the operands).
//  K4 k_comb : per batch, 4 waves: alpha <- Q_s alpha (s ascending), fp8 LUT
//              decode, x2^-7 per segment. LL_b = log(sum/128) - T*log(V).
//  K5 k_final: out = -sum_b ll[b]

#define KK 128
#define TT 2048
#define BB 64

typedef int v8i __attribute__((ext_vector_type(8)));
typedef float v4f __attribute__((ext_vector_type(4)));

__device__ __forceinline__ float wave_sum64(float v) {
#pragma unroll
  for (int m = 32; m; m >>= 1) v += __shfl_xor(v, m, 64);
  return v;
}
__device__ __forceinline__ float wave_max64(float v) {
#pragma unroll
  for (int m = 32; m; m >>= 1) v = fmaxf(v, __shfl_xor(v, m, 64));
  return v;
}
// f32 -> bf16 round-to-nearest-even (positive normals here)
__device__ __forceinline__ unsigned short f2bf(float x) {
  union { float f; unsigned u; } c; c.f = x;
  unsigned r = c.u + 0x7fffu + ((c.u >> 16) & 1u);
  return (unsigned short)(r >> 16);
}
__device__ __forceinline__ float bflo(unsigned u) {
  union { unsigned u; float f; } c; c.u = u << 16; return c.f;
}
__device__ __forceinline__ float bfhi(unsigned u) {
  union { unsigned u; float f; } c; c.u = u & 0xffff0000u; return c.f;
}

// ---------------- K1: emission table E128 (V x K, bf16 of 128*e) ----------
__global__ __launch_bounds__(128, 1)
void k_emis(const float* __restrict__ tag, const float* __restrict__ word,
            const float* __restrict__ bias, unsigned short* __restrict__ E128,
            float* __restrict__ partialZ, int V) {
  __shared__ float4 wtile[128 * 32];
  __shared__ float btile[128];
  const int tid = threadIdx.x;
  const int v0 = blockIdx.x * 128;

  const float4* w4 = (const float4*)word;
  const int maxi = V * 32 - 1;
#pragma unroll
  for (int it = 0; it < 32; ++it) {
    int idx = it * 128 + tid;
    int g = v0 * 32 + idx;
    wtile[idx] = w4[min(g, maxi)];
  }
  btile[tid] = (v0 + tid < V) ? bias[v0 + tid] : 0.f;

  float treg[128];
  const float4* t4 = (const float4*)(tag + (size_t)tid * 128);
#pragma unroll
  for (int c = 0; c < 32; ++c) {
    float4 x = t4[c];
    treg[4 * c + 0] = x.x; treg[4 * c + 1] = x.y;
    treg[4 * c + 2] = x.z; treg[4 * c + 3] = x.w;
  }
  __syncthreads();

  float zp = 0.f;
  for (int v = 0; v < 128; ++v) {
    if (v0 + v >= V) break;  // uniform
    const float4* row = &wtile[v * 32];
    float a0 = 0.f, a1 = 0.f, a2 = 0.f, a3 = 0.f;
#pragma unroll
    for (int c = 0; c < 32; ++c) {
      float4 pv = row[c];
      a0 = fmaf(pv.x, treg[4 * c + 0], a0);
      a1 = fmaf(pv.y, treg[4 * c + 1], a1);
      a2 = fmaf(pv.z, treg[4 * c + 2], a2);
      a3 = fmaf(pv.w, treg[4 * c + 3], a3);
    }
    float e = __expf((a0 + a1) + (a2 + a3) + btile[v]);
    E128[(size_t)(v0 + v) * KK + tid] = f2bf(128.f * e);
    zp += e;
  }
  partialZ[(size_t)blockIdx.x * KK + tid] = zp;
}

// ---------------- K2: transition matrix + piZ/piPlain/Zinv/A2p ------------
__global__ __launch_bounds__(128)
void k_trans(const float* __restrict__ W, const float* __restrict__ q,
             const float* __restrict__ tb, const float* __restrict__ pZ,
             const float* __restrict__ initlog, float* __restrict__ A2,
             float* __restrict__ A2p, float* __restrict__ piZ,
             float* __restrict__ piPlain, float* __restrict__ Zinv,
             int nPart, int V) {
  __shared__ float qs[KK];
  __shared__ float r0[2], r1[2];
  const int j = threadIdx.x, i = blockIdx.x;
  qs[j] = q[j];
  __syncthreads();

  const float4* w4 = (const float4*)(W + ((size_t)(i * KK + j)) * KK);
  const float4* q4 = (const float4*)qs;
  float a0 = 0.f, a1 = 0.f, a2 = 0.f, a3 = 0.f;
#pragma unroll
  for (int c = 0; c < KK / 4; ++c) {
    float4 wv = w4[c], qv = q4[c];
    a0 = fmaf(wv.x, qv.x, a0); a1 = fmaf(wv.y, qv.y, a1);
    a2 = fmaf(wv.z, qv.z, a2); a3 = fmaf(wv.w, qv.w, a3);
  }
  float logit = (a0 + a1) + (a2 + a3) + tb[i * KK + j];

  float m = wave_max64(logit);
  if ((j & 63) == 0) r0[j >> 6] = m;
  __syncthreads();
  m = fmaxf(r0[0], r0[1]);
  float e = __expf(logit - m);
  float s = wave_sum64(e);
  if ((j & 63) == 0) r1[j >> 6] = s;
  __syncthreads();
  s = r1[0] + r1[1];

  float Z0 = 0.f, Z1 = 0.f, Z2 = 0.f, Z3 = 0.f;
  float Z4 = 0.f, Z5 = 0.f, Z6 = 0.f, Z7 = 0.f;
  int p = 0;
  for (; p + 8 <= nPart; p += 8) {
    Z0 += pZ[(size_t)(p + 0) * KK + j]; Z1 += pZ[(size_t)(p + 1) * KK + j];
    Z2 += pZ[(size_t)(p + 2) * KK + j]; Z3 += pZ[(size_t)(p + 3) * KK + j];
    Z4 += pZ[(size_t)(p + 4) * KK + j]; Z5 += pZ[(size_t)(p + 5) * KK + j];
    Z6 += pZ[(size_t)(p + 6) * KK + j]; Z7 += pZ[(size_t)(p + 7) * KK + j];
  }
  for (; p < nPart; ++p) Z0 += pZ[(size_t)p * KK + j];
  float Z = ((Z0 + Z1) + (Z2 + Z3)) + ((Z4 + Z5) + (Z6 + Z7));

  A2[i * KK + j] = e / (s * Z);        // fallback path (Z-folded)
  A2p[i * KK + j] = 128.0f * e / s;    // scan path: pure softmax x128 (~1.0)

  if (i == 0) {
    float x = initlog[j];
    __syncthreads();
    float m2 = wave_max64(x);
    if ((j & 63) == 0) r0[j >> 6] = m2;
    __syncthreads();
    m2 = fmaxf(r0[0], r0[1]);
    float e2 = __expf(x - m2);
    float s2 = wave_sum64(e2);
    if ((j & 63) == 0) r1[j >> 6] = s2;
    __syncthreads();
    s2 = r1[0] + r1[1];
    piZ[j] = e2 / (s2 * Z);
    piPlain[j] = e2 / s2;
    Zinv[j] = (float)V / Z;
  }
}

// ---------------- K3: segmented matrix scan (MX-FP8), template NSEG -------
// NS*64 blocks x 64 thr (1 wave). chain = s*64+b. lane: m = l&15, g = l>>4.
//   af[it] word w byte c : A2p[16w+4g+c][16it+m] * Zinv[16it+m]   (A-operand)
//   Q[jt]  word w byte c : Qstored[row 16w+4g+c][col 16jt+m]      (B-operand)
//   D(it,jt) lane reg r  -> row 16it+4g+r, col 16jt+m  -> Q[jt] word it.
// Step: Qstored <- 128*( diag(E*zi) A^T Qtrue );  SA=SB=2^-7.
__device__ __forceinline__ void scan_step(
    int n, int nst, const int* __restrict__ tks,
    const unsigned short* __restrict__ E128, const v8i (&af)[8], v8i (&Q)[8],
    uint2 (&evU)[8], uint2 (&evL)[8], int g) {
  // prefetch next step's e-row (consumed ~one full step later)
  int np = (n + 1 < nst) ? n + 1 : nst - 1;
  const unsigned short* ern = E128 + (size_t)tks[np] * KK;
#pragma unroll
  for (int it = 0; it < 8; ++it)
    evL[it] = *(const uint2*)(ern + 16 * it + 4 * g);

  // expand e to f32 once per step (pk-friendly v4f)
  v4f ev4[8];
#pragma unroll
  for (int it = 0; it < 8; ++it) {
    ev4[it][0] = bflo(evU[it].x); ev4[it][1] = bfhi(evU[it].x);
    ev4[it][2] = bflo(evU[it].y); ev4[it][3] = bfhi(evU[it].y);
  }

  const v4f ZED = {0.f, 0.f, 0.f, 0.f};
#pragma unroll
  for (int jt = 0; jt < 8; ++jt) {
    v4f acc[8];
#pragma unroll
    for (int it = 0; it < 8; ++it)
      acc[it] = __builtin_amdgcn_mfma_scale_f32_16x16x128_f8f6f4(
          af[it], Q[jt], ZED, 0, 0, 0, 0x78787878, 0, 0x78787878);
#pragma unroll
    for (int it = 0; it < 8; ++it) {
      v4f nn = acc[it] * ev4[it];  // v_pk_mul_f32 x2
      int w = __builtin_amdgcn_cvt_pk_fp8_f32(nn[0], nn[1], 0, false);
      w = __builtin_amdgcn_cvt_pk_fp8_f32(nn[2], nn[3], w, true);
      Q[jt][it] = w;
    }
  }
}

template <int NS>
__global__ __launch_bounds__(64, 4)
void k_scan(const int* __restrict__ toks, const unsigned short* __restrict__ E128,
            const float* __restrict__ A2p, const float* __restrict__ Zinv,
            uint4* __restrict__ P) {
  constexpr int SEGL = TT / NS;
  __shared__ int tks[SEGL];
  const int chain = blockIdx.x;
  const int s = chain >> 6;
  const int b = chain & 63;
  const int l = threadIdx.x, m = l & 15, g = l >> 4;
  const int t0 = SEGL * s + 1;
  const int nst = (s == NS - 1) ? SEGL - 1 : SEGL;  // t <= 2047
  if (l < nst) tks[l] = toks[(size_t)b * TT + t0 + l];

  // static A-operand: A2p with Zinv folded into output columns
  v8i af[8];
#pragma unroll
  for (int it = 0; it < 8; ++it) {
    const int colj = 16 * it + m;
    const float zj = Zinv[colj];
#pragma unroll
    for (int w = 0; w < 8; ++w) {
      const float* ap = A2p + (size_t)(16 * w + 4 * g) * KK + colj;
      int ww = __builtin_amdgcn_cvt_pk_fp8_f32(ap[0] * zj, ap[KK] * zj, 0, false);
      ww = __builtin_amdgcn_cvt_pk_fp8_f32(ap[2 * KK] * zj, ap[3 * KK] * zj, ww, true);
      af[it][w] = ww;
    }
  }

  // Q = 128 * Identity (fp8 0x70 = 128.0 at row==col)
  v8i Q[8];
  const unsigned diag = (g == (m >> 2)) ? (0x70u << (8 * (m & 3))) : 0u;
#pragma unroll
  for (int jt = 0; jt < 8; ++jt) {
#pragma unroll
    for (int w = 0; w < 8; ++w) Q[jt][w] = (w == jt) ? (int)diag : 0;
  }

  __syncthreads();

  uint2 evA[8], evB[8];
  {
    const unsigned short* er0 = E128 + (size_t)tks[0] * KK;
#pragma unroll
    for (int it = 0; it < 8; ++it) evA[it] = *(const uint2*)(er0 + 16 * it + 4 * g);
  }
  const int pairs = nst >> 1;
  for (int c = 0; c < pairs; ++c) {
    scan_step(2 * c + 0, nst, tks, E128, af, Q, evA, evB, g);
    scan_step(2 * c + 1, nst, tks, E128, af, Q, evB, evA, g);
  }
  if (nst & 1) scan_step(nst - 1, nst, tks, E128, af, Q, evA, evB, g);

  // dump Q (per-lane natural order; combine uses the same indexing)
  uint4* base = P + (size_t)chain * 1024;
#pragma unroll
  for (int jt = 0; jt < 8; ++jt) {
    union { v8i v; uint4 u[2]; } x; x.v = Q[jt];
    base[jt * 128 + l * 2 + 0] = x.u[0];
    base[jt * 128 + l * 2 + 1] = x.u[1];
  }
}

// ---------------- K4: combine segments per batch (4 waves) ----------------
// alpha^T <- Q_s alpha^T, s ascending. 256 thr: wave h handles word-pairs
// w in {2h, 2h+1} (rows [32h, 32h+32)). Lane (m,g): cols {16jt+m}, its bytes
// rows {16w+4g+c}; reduce partial row-sums over the 16 m-lanes, 2 barriers/s.
__global__ __launch_bounds__(256, 1)
void k_comb(const uint4* __restrict__ P, const float* __restrict__ piPlain,
            const unsigned short* __restrict__ E128, const float* __restrict__ Zinv,
            const int* __restrict__ toks, float* __restrict__ ll, int V,
            int nseg) {
  __shared__ float alpha[KK];
  __shared__ float lut[256];
  const int b = blockIdx.x;
  const int tid = threadIdx.x;
  const int h = tid >> 6;
  const int l = tid & 63, m = l & 15, g = l >> 4;

  // e4m3fn decode LUT (bias 7, denormals m*2^-9)
  if (tid < 256) {
    int ex = (tid >> 3) & 15, mt = tid & 7;
    float v = (ex == 0) ? ldexpf((float)mt, -9)
                        : ldexpf(1.f + (float)mt * 0.125f, ex - 7);
    lut[tid] = (tid & 0x80) ? -v : v;
  }
  if (tid < KK) {  // alpha_1 = pi * E*zi (stored = true*128 via E128's x128)
    int tok0 = toks[(size_t)b * TT];
    alpha[tid] = piPlain[tid] * bflo((unsigned)E128[(size_t)tok0 * KK + tid]) *
                 Zinv[tid];
  }
  __syncthreads();

  const unsigned* P32 = (const unsigned*)P;
  for (int s = 0; s < nseg; ++s) {
    const size_t cbase = ((size_t)(s * 64 + b)) * 4096;
    float ac[8];
#pragma unroll
    for (int jt = 0; jt < 8; ++jt) ac[jt] = alpha[16 * jt + m];
    float out[8];  // [w2][c]
#pragma unroll
    for (int k = 0; k < 8; ++k) out[k] = 0.f;
#pragma unroll
    for (int jt = 0; jt < 8; ++jt) {
      const float aj = ac[jt];
#pragma unroll
      for (int w2 = 0; w2 < 2; ++w2) {
        unsigned wd = P32[cbase + jt * 512 + l * 8 + (2 * h + w2)];
#pragma unroll
        for (int c = 0; c < 4; ++c) {
          float v = lut[(wd >> (8 * c)) & 0xffu];
          out[w2 * 4 + c] = fmaf(v, aj, out[w2 * 4 + c]);
        }
      }
    }
    __syncthreads();  // all alpha reads done before overwrite
#pragma unroll
    for (int k = 0; k < 8; ++k) {
      out[k] += __shfl_xor(out[k], 1, 64);
      out[k] += __shfl_xor(out[k], 2, 64);
      out[k] += __shfl_xor(out[k], 4, 64);
      out[k] += __shfl_xor(out[k], 8, 64);
    }
    if (m == 0) {
#pragma unroll
      for (int w2 = 0; w2 < 2; ++w2)
#pragma unroll
        for (int c = 0; c < 4; ++c)
          alpha[16 * (2 * h + w2) + 4 * g + c] =
              out[w2 * 4 + c] * 0.0078125f;  // keep stored = true*128
    }
    __syncthreads();
  }

  if (h == 0) {
    float sm = alpha[l] + alpha[l + 64];
    sm = wave_sum64(sm);
    const float C = (float)(log(128.0) + (double)TT * log((double)V));
    if (l == 0) ll[b] = __logf(sm) - C;
  }
}

// ---------------- fallback (round-3 path; E bf16 x128) --------------------
__global__ __launch_bounds__(256, 1)
void k_fwd_fb(const int* __restrict__ toks, const unsigned short* __restrict__ E128,
              const float* __restrict__ A2, const float* __restrict__ piZ,
              float* __restrict__ ll) {
  __shared__ float pb[2][KK];
  __shared__ float part[2 * KK];
  __shared__ int tk[TT];
  __shared__ float red[4];
  const int tid = threadIdx.x;
  const int j = tid & (KK - 1);
  const int h = tid >> 7;
  const int b = blockIdx.x;

  const int4* t4 = (const int4*)(toks + (size_t)b * TT);
  int4* l4 = (int4*)tk;
#pragma unroll
  for (int c = 0; c < TT / 4 / 256; ++c) l4[c * 256 + tid] = t4[c * 256 + tid];

  float Areg[64];
  {
    const float* Acol = A2 + (size_t)(h * 64) * KK + j;
#pragma unroll
    for (int i = 0; i < 64; ++i) Areg[i] = Acol[i * KK];
  }
  __syncthreads();

  const unsigned short* Ej = E128 + j;
  const float inv128 = 0.0078125f;
  float eA = inv128 * bflo((unsigned)Ej[(size_t)tk[1] * KK]);
  float eB = inv128 * bflo((unsigned)Ej[(size_t)tk[2] * KK]);
  float eC = inv128 * bflo((unsigned)Ej[(size_t)tk[3] * KK]);
  float eD = inv128 * bflo((unsigned)Ej[(size_t)tk[4] * KK]);
  if (h == 0) pb[0][j] = piZ[j] * inv128 * bflo((unsigned)Ej[(size_t)tk[0] * KK]);
  float Lacc = 0.f;
  __syncthreads();

  for (int t = 1; t < TT; ++t) {
    const float4* ph = (const float4*)&pb[(t - 1) & 1][h * 64];
    float a0 = 0.f, a1 = 0.f, a2 = 0.f, a3 = 0.f;
#pragma unroll
    for (int c = 0; c < 16; ++c) {
      float4 pv = ph[c];
      a0 = fmaf(pv.x, Areg[4 * c + 0], a0);
      a1 = fmaf(pv.y, Areg[4 * c + 1], a1);
      a2 = fmaf(pv.z, Areg[4 * c + 2], a2);
      a3 = fmaf(pv.w, Areg[4 * c + 3], a3);
    }
    part[2 * j + h] = (a0 + a1) + (a2 + a3);
    __syncthreads();

    float e = eA; eA = eB; eB = eC; eC = eD;
    int tn = tk[t + 4 < TT ? t + 4 : TT - 1];
    eD = inv128 * bflo((unsigned)Ej[(size_t)tn * KK]);

    float np = 0.f;
    if (h == 0) {
      float2 pr = *(const float2*)&part[2 * j];
      np = (pr.x + pr.y) * e;
    }
    if ((t & 63) == 0) {
      float v = wave_sum64(np);
      if ((tid & 63) == 0) red[tid >> 6] = v;
      __syncthreads();
      float tot = (red[0] + red[1]) + (red[2] + red[3]);
      np *= __builtin_amdgcn_rcpf(tot);
      if (tid == 0) Lacc += __logf(tot);
    } else if ((t & 3) == 0) {
      np *= 0x1p64f;
    }
    if (h == 0) pb[t & 1][j] = np;
    __syncthreads();
  }

  float lv = (h == 0) ? pb[(TT - 1) & 1][j] : 0.f;
  float v = wave_sum64(lv);
  if ((tid & 63) == 0) red[tid >> 6] = v;
  __syncthreads();
  float tot = (red[0] + red[1]) + (red[2] + red[3]);
  const float RESCALE_C = (float)(30720.0 * 0.6931471805599453);
  if (tid == 0) ll[b] = Lacc + __logf(tot) - RESCALE_C;
}

// ---------------- K5: final reduction ----------------
__global__ void k_final(const float* __restrict__ ll, float* __restrict__ out) {
  float v = ll[threadIdx.x];
  v = wave_sum64(v);
  if (threadIdx.x == 0) out[0] = -v;
}

extern "C" void kernel_launch(void* const* d_in, const int* in_sizes, int n_in,
                              void* d_out, int out_size, void* d_ws, size_t ws_size,
                              hipStream_t stream) {
  const int*   toks    = (const int*)d_in[0];
  const float* initlog = (const float*)d_in[1];
  const float* tag     = (const float*)d_in[2];
  const float* word    = (const float*)d_in[3];
  const float* bias    = (const float*)d_in[4];
  const float* q       = (const float*)d_in[5];
  const float* W       = (const float*)d_in[6];
  const float* tb      = (const float*)d_in[7];
  float* out = (float*)d_out;

  const int V = in_sizes[4];
  const int nPart = (V + 127) / 128;

  unsigned short* E128 = (unsigned short*)d_ws;        // V*128 bf16
  float* pZ      = (float*)(E128 + (size_t)V * KK);    // nPart*128
  float* A2      = pZ + (size_t)nPart * KK;            // 128^2 (fb)
  float* A2p     = A2 + KK * KK;                       // 128^2
  float* piZ     = A2p + KK * KK;                      // 128 (fb)
  float* piPlain = piZ + KK;                           // 128
  float* Zinv    = piPlain + KK;                       // 128
  float* ll      = Zinv + KK;                          // 64
  uintptr_t pp = (uintptr_t)(ll + BB);
  pp = (pp + 15) & ~(uintptr_t)15;
  uint4* P = (uint4*)pp;

  const size_t head = pp - (uintptr_t)d_ws;
  const size_t need64 = head + (size_t)64 * BB * 1024 * sizeof(uint4);  // 64MB P
  const size_t need32 = head + (size_t)32 * BB * 1024 * sizeof(uint4);  // 32MB P

  k_emis <<<nPart, 128, 0, stream>>>(tag, word, bias, E128, pZ, V);
  k_trans<<<KK, 128, 0, stream>>>(W, q, tb, pZ, initlog, A2, A2p, piZ,
                                  piPlain, Zinv, nPart, V);
  if (ws_size >= need64) {
    k_scan<64><<<64 * BB, 64, 0, stream>>>(toks, E128, A2p, Zinv, P);
    k_comb<<<BB, 256, 0, stream>>>(P, piPlain, E128, Zinv, toks, ll, V, 64);
  } else if (ws_size >= need32) {
    k_scan<32><<<32 * BB, 64, 0, stream>>>(toks, E128, A2p, Zinv, P);
    k_comb<<<BB, 256, 0, stream>>>(P, piPlain, E128, Zinv, toks, ll, V, 32);
  } else {
    k_fwd_fb<<<BB, 256, 0, stream>>>(toks, E128, A2, piZ, ll);
  }
  k_final<<<1, BB, 0, stream>>>(ll, out);
}

// Round 11
// 1638.192 us; speedup vs baseline: 1.9525x; 1.9525x over previous
//
#include <hip/hip_runtime.h>

// Neural HMM forward-algorithm NLL.  K=128, V=50257, D=H=128, B=64, T=2048.
//
// Associative scan over t: alpha_t = alpha_{t-1} M_t  (M_t = A diag(e_t)).
// NS segments x 64 batches independent chains, each propagating a 128x128
// matrix Q <- diag(e_t) A^T Q via MX-FP8 MFMA (mfma_scale 16x16x128).
// r9: NSEG=32 -> 2 waves/SIMD (grid-limited), MfmaUtil 46%, scan 246 us.
// r10 ERRATum: launch_bounds(64,4) caps regs at 128 < live state (~150) ->
// scratch spill catastrophe (9.7 GB HBM). 4 waves/SIMD is reg-infeasible;
// 3 waves (cap 170 >= natural ~144) is the feasible rung -> NSEG=48,
// launch_bounds(64,3), r9's proven step body.
//
//  K1 k_emis : E128[v][k] = bf16(128*exp(tag_k . word_v + bias_v)) + partial Z
//  K2 k_trans: A2 (Z-folded, fb), A2p = 128*softmax rows, piZ (fb),
//              piPlain = softmax(init), Zinv[j] = V/Z_j
//  K3 k_scan<NS> : per chain: Q init I*128 (fp8), ~2047/NS steps of
//              Qstored <- 128 * diag(E*V/Z) A^T Qtrue (stored = true*128;
//              SA=SB=2^-7 cancel the two x128 of the operands).
//  K4 k_comb : per batch, 4 waves: alpha <- Q_s alpha (s ascending),
//              HW v_cvt_f32_fp8 decode, x2^-7 per segment.
//              LL_b = log(sum/128) - T*log(V).
//  K5 k_final: out = -sum_b ll[b]

#define KK 128
#define TT 2048
#define BB 64

typedef int v8i __attribute__((ext_vector_type(8)));
typedef float v4f __attribute__((ext_vector_type(4)));

__device__ __forceinline__ float wave_sum64(float v) {
#pragma unroll
  for (int m = 32; m; m >>= 1) v += __shfl_xor(v, m, 64);
  return v;
}
__device__ __forceinline__ float wave_max64(float v) {
#pragma unroll
  for (int m = 32; m; m >>= 1) v = fmaxf(v, __shfl_xor(v, m, 64));
  return v;
}
// f32 -> bf16 round-to-nearest-even (positive normals here)
__device__ __forceinline__ unsigned short f2bf(float x) {
  union { float f; unsigned u; } c; c.f = x;
  unsigned r = c.u + 0x7fffu + ((c.u >> 16) & 1u);
  return (unsigned short)(r >> 16);
}
__device__ __forceinline__ float bflo(unsigned u) {
  union { unsigned u; float f; } c; c.u = u << 16; return c.f;
}
__device__ __forceinline__ float bfhi(unsigned u) {
  union { unsigned u; float f; } c; c.u = u & 0xffff0000u; return c.f;
}

// fp8 e4m3fn byte -> f32 (ALU fallback handles denormals; positive data)
__device__ __forceinline__ float fp8dec_sw(unsigned byte) {
  unsigned em = byte & 0x7fu;
  float v;
  if (em < 8) {
    v = (float)em * 0x1p-9f;
  } else {
    union { unsigned u; float f; } x;
    x.u = (em << 20) + (120u << 23);
    v = x.f;
  }
  return (byte & 0x80u) ? -v : v;
}

// ---------------- K1: emission table E128 (V x K, bf16 of 128*e) ----------
__global__ __launch_bounds__(128, 1)
void k_emis(const float* __restrict__ tag, const float* __restrict__ word,
            const float* __restrict__ bias, unsigned short* __restrict__ E128,
            float* __restrict__ partialZ, int V) {
  __shared__ float4 wtile[128 * 32];
  __shared__ float btile[128];
  const int tid = threadIdx.x;
  const int v0 = blockIdx.x * 128;

  const float4* w4 = (const float4*)word;
  const int maxi = V * 32 - 1;
#pragma unroll
  for (int it = 0; it < 32; ++it) {
    int idx = it * 128 + tid;
    int g = v0 * 32 + idx;
    wtile[idx] = w4[min(g, maxi)];
  }
  btile[tid] = (v0 + tid < V) ? bias[v0 + tid] : 0.f;

  float treg[128];
  const float4* t4 = (const float4*)(tag + (size_t)tid * 128);
#pragma unroll
  for (int c = 0; c < 32; ++c) {
    float4 x = t4[c];
    treg[4 * c + 0] = x.x; treg[4 * c + 1] = x.y;
    treg[4 * c + 2] = x.z; treg[4 * c + 3] = x.w;
  }
  __syncthreads();

  float zp = 0.f;
  for (int v = 0; v < 128; ++v) {
    if (v0 + v >= V) break;  // uniform
    const float4* row = &wtile[v * 32];
    float a0 = 0.f, a1 = 0.f, a2 = 0.f, a3 = 0.f;
#pragma unroll
    for (int c = 0; c < 32; ++c) {
      float4 pv = row[c];
      a0 = fmaf(pv.x, treg[4 * c + 0], a0);
      a1 = fmaf(pv.y, treg[4 * c + 1], a1);
      a2 = fmaf(pv.z, treg[4 * c + 2], a2);
      a3 = fmaf(pv.w, treg[4 * c + 3], a3);
    }
    float e = __expf((a0 + a1) + (a2 + a3) + btile[v]);
    E128[(size_t)(v0 + v) * KK + tid] = f2bf(128.f * e);
    zp += e;
  }
  partialZ[(size_t)blockIdx.x * KK + tid] = zp;
}

// ---------------- K2: transition matrix + piZ/piPlain/Zinv/A2p ------------
__global__ __launch_bounds__(128)
void k_trans(const float* __restrict__ W, const float* __restrict__ q,
             const float* __restrict__ tb, const float* __restrict__ pZ,
             const float* __restrict__ initlog, float* __restrict__ A2,
             float* __restrict__ A2p, float* __restrict__ piZ,
             float* __restrict__ piPlain, float* __restrict__ Zinv,
             int nPart, int V) {
  __shared__ float qs[KK];
  __shared__ float r0[2], r1[2];
  const int j = threadIdx.x, i = blockIdx.x;
  qs[j] = q[j];
  __syncthreads();

  const float4* w4 = (const float4*)(W + ((size_t)(i * KK + j)) * KK);
  const float4* q4 = (const float4*)qs;
  float a0 = 0.f, a1 = 0.f, a2 = 0.f, a3 = 0.f;
#pragma unroll
  for (int c = 0; c < KK / 4; ++c) {
    float4 wv = w4[c], qv = q4[c];
    a0 = fmaf(wv.x, qv.x, a0); a1 = fmaf(wv.y, qv.y, a1);
    a2 = fmaf(wv.z, qv.z, a2); a3 = fmaf(wv.w, qv.w, a3);
  }
  float logit = (a0 + a1) + (a2 + a3) + tb[i * KK + j];

  float m = wave_max64(logit);
  if ((j & 63) == 0) r0[j >> 6] = m;
  __syncthreads();
  m = fmaxf(r0[0], r0[1]);
  float e = __expf(logit - m);
  float s = wave_sum64(e);
  if ((j & 63) == 0) r1[j >> 6] = s;
  __syncthreads();
  s = r1[0] + r1[1];

  float Z0 = 0.f, Z1 = 0.f, Z2 = 0.f, Z3 = 0.f;
  float Z4 = 0.f, Z5 = 0.f, Z6 = 0.f, Z7 = 0.f;
  int p = 0;
  for (; p + 8 <= nPart; p += 8) {
    Z0 += pZ[(size_t)(p + 0) * KK + j]; Z1 += pZ[(size_t)(p + 1) * KK + j];
    Z2 += pZ[(size_t)(p + 2) * KK + j]; Z3 += pZ[(size_t)(p + 3) * KK + j];
    Z4 += pZ[(size_t)(p + 4) * KK + j]; Z5 += pZ[(size_t)(p + 5) * KK + j];
    Z6 += pZ[(size_t)(p + 6) * KK + j]; Z7 += pZ[(size_t)(p + 7) * KK + j];
  }
  for (; p < nPart; ++p) Z0 += pZ[(size_t)p * KK + j];
  float Z = ((Z0 + Z1) + (Z2 + Z3)) + ((Z4 + Z5) + (Z6 + Z7));

  A2[i * KK + j] = e / (s * Z);        // fallback path (Z-folded)
  A2p[i * KK + j] = 128.0f * e / s;    // scan path: pure softmax x128 (~1.0)

  if (i == 0) {
    float x = initlog[j];
    __syncthreads();
    float m2 = wave_max64(x);
    if ((j & 63) == 0) r0[j >> 6] = m2;
    __syncthreads();
    m2 = fmaxf(r0[0], r0[1]);
    float e2 = __expf(x - m2);
    float s2 = wave_sum64(e2);
    if ((j & 63) == 0) r1[j >> 6] = s2;
    __syncthreads();
    s2 = r1[0] + r1[1];
    piZ[j] = e2 / (s2 * Z);
    piPlain[j] = e2 / s2;
    Zinv[j] = (float)V / Z;
  }
}

// ---------------- K3: segmented matrix scan (MX-FP8), template NSEG -------
// NS*64 blocks x 64 thr (1 wave). chain = s*64+b. lane: m = l&15, g = l>>4.
//   af[it] word w byte c : A2p[16w+4g+c][16it+m] * Zinv[16it+m]   (A-operand)
//   Q[jt]  word w byte c : Qstored[row 16w+4g+c][col 16jt+m]      (B-operand)
//   D(it,jt) lane reg r  -> row 16it+4g+r, col 16jt+m  -> Q[jt] word it.
// Step: Qstored <- 128*( diag(E*zi) A^T Qtrue );  SA=SB=2^-7.
// Step body = r9's proven version (112 VGPR, no spill).
__device__ __forceinline__ void scan_step(
    int n, int nst, const int* __restrict__ tks,
    const unsigned short* __restrict__ E128, const v8i (&af)[8], v8i (&Q)[8],
    uint2 (&evU)[8], uint2 (&evL)[8], int g) {
  // prefetch next step's e-row (consumed ~one full step later)
  int np = (n + 1 < nst) ? n + 1 : nst - 1;
  const unsigned short* ern = E128 + (size_t)tks[np] * KK;
#pragma unroll
  for (int it = 0; it < 8; ++it)
    evL[it] = *(const uint2*)(ern + 16 * it + 4 * g);

  const v4f ZED = {0.f, 0.f, 0.f, 0.f};
#pragma unroll
  for (int jt = 0; jt < 8; ++jt) {
    v4f acc[8];
#pragma unroll
    for (int it = 0; it < 8; ++it)
      acc[it] = __builtin_amdgcn_mfma_scale_f32_16x16x128_f8f6f4(
          af[it], Q[jt], ZED, 0, 0, 0, 0x78787878, 0, 0x78787878);
#pragma unroll
    for (int it = 0; it < 8; ++it) {
      float e0 = bflo(evU[it].x), e1 = bfhi(evU[it].x);
      float e2 = bflo(evU[it].y), e3 = bfhi(evU[it].y);
      int w = __builtin_amdgcn_cvt_pk_fp8_f32(acc[it][0] * e0, acc[it][1] * e1, 0, false);
      w = __builtin_amdgcn_cvt_pk_fp8_f32(acc[it][2] * e2, acc[it][3] * e3, w, true);
      Q[jt][it] = w;
    }
  }
}

template <int NS>
__global__ __launch_bounds__(64, 3)
void k_scan(const int* __restrict__ toks, const unsigned short* __restrict__ E128,
            const float* __restrict__ A2p, const float* __restrict__ Zinv,
            uint4* __restrict__ P) {
  __shared__ int tks[64];  // max segment length (NS >= 32)
  const int chain = blockIdx.x;
  const int s = chain >> 6;
  const int b = chain & 63;
  const int l = threadIdx.x, m = l & 15, g = l >> 4;
  // segments tile t = 1..2047 (2047 steps), uneven lengths allowed
  const int t0 = 1 + (2047 * s) / NS;
  const int nst = (2047 * (s + 1)) / NS - (2047 * s) / NS;
  if (l < nst) tks[l] = toks[(size_t)b * TT + t0 + l];

  // static A-operand: A2p with Zinv folded into output columns
  v8i af[8];
#pragma unroll
  for (int it = 0; it < 8; ++it) {
    const int colj = 16 * it + m;
    const float zj = Zinv[colj];
#pragma unroll
    for (int w = 0; w < 8; ++w) {
      const float* ap = A2p + (size_t)(16 * w + 4 * g) * KK + colj;
      int ww = __builtin_amdgcn_cvt_pk_fp8_f32(ap[0] * zj, ap[KK] * zj, 0, false);
      ww = __builtin_amdgcn_cvt_pk_fp8_f32(ap[2 * KK] * zj, ap[3 * KK] * zj, ww, true);
      af[it][w] = ww;
    }
  }

  // Q = 128 * Identity (fp8 0x70 = 128.0 at row==col)
  v8i Q[8];
  const unsigned diag = (g == (m >> 2)) ? (0x70u << (8 * (m & 3))) : 0u;
#pragma unroll
  for (int jt = 0; jt < 8; ++jt) {
#pragma unroll
    for (int w = 0; w < 8; ++w) Q[jt][w] = (w == jt) ? (int)diag : 0;
  }

  __syncthreads();

  uint2 evA[8], evB[8];
  {
    const unsigned short* er0 = E128 + (size_t)tks[0] * KK;
#pragma unroll
    for (int it = 0; it < 8; ++it) evA[it] = *(const uint2*)(er0 + 16 * it + 4 * g);
  }
  const int pairs = nst >> 1;
  for (int c = 0; c < pairs; ++c) {
    scan_step(2 * c + 0, nst, tks, E128, af, Q, evA, evB, g);
    scan_step(2 * c + 1, nst, tks, E128, af, Q, evB, evA, g);
  }
  if (nst & 1) scan_step(nst - 1, nst, tks, E128, af, Q, evA, evB, g);

  // dump Q (per-lane natural order; combine uses the same indexing)
  uint4* base = P + (size_t)chain * 1024;
#pragma unroll
  for (int jt = 0; jt < 8; ++jt) {
    union { v8i v; uint4 u[2]; } x; x.v = Q[jt];
    base[jt * 128 + l * 2 + 0] = x.u[0];
    base[jt * 128 + l * 2 + 1] = x.u[1];
  }
}

// ---------------- K4: combine segments per batch (4 waves) ----------------
// alpha^T <- Q_s alpha^T, s ascending. 256 thr: wave h handles word-pairs
// w in {2h, 2h+1} (rows [32h, 32h+32)). Lane (m,g): cols {16jt+m}, its bytes
// rows {16w+4g+c}; reduce partial row-sums over the 16 m-lanes, 2 barriers/s.
// fp8 decode via HW v_cvt_f32_fp8 (no LDS LUT).
__global__ __launch_bounds__(256, 1)
void k_comb(const uint4* __restrict__ P, const float* __restrict__ piPlain,
            const unsigned short* __restrict__ E128, const float* __restrict__ Zinv,
            const int* __restrict__ toks, float* __restrict__ ll, int V,
            int nseg) {
  __shared__ float alpha[KK];
  const int b = blockIdx.x;
  const int tid = threadIdx.x;
  const int h = tid >> 6;
  const int l = tid & 63, m = l & 15, g = l >> 4;

  if (tid < KK) {  // alpha_1 = pi * E*zi (stored = true*128 via E128's x128)
    int tok0 = toks[(size_t)b * TT];
    alpha[tid] = piPlain[tid] * bflo((unsigned)E128[(size_t)tok0 * KK + tid]) *
                 Zinv[tid];
  }
  __syncthreads();

  const unsigned* P32 = (const unsigned*)P;
  for (int s = 0; s < nseg; ++s) {
    const size_t cbase = ((size_t)(s * 64 + b)) * 4096;
    float ac[8];
#pragma unroll
    for (int jt = 0; jt < 8; ++jt) ac[jt] = alpha[16 * jt + m];
    float out[8];  // [w2][c]
#pragma unroll
    for (int k = 0; k < 8; ++k) out[k] = 0.f;
#pragma unroll
    for (int jt = 0; jt < 8; ++jt) {
      const float aj = ac[jt];
#pragma unroll
      for (int w2 = 0; w2 < 2; ++w2) {
        unsigned wd = P32[cbase + jt * 512 + l * 8 + (2 * h + w2)];
#if __has_builtin(__builtin_amdgcn_cvt_f32_fp8)
        out[w2 * 4 + 0] = fmaf(__builtin_amdgcn_cvt_f32_fp8((int)wd, 0), aj, out[w2 * 4 + 0]);
        out[w2 * 4 + 1] = fmaf(__builtin_amdgcn_cvt_f32_fp8((int)wd, 1), aj, out[w2 * 4 + 1]);
        out[w2 * 4 + 2] = fmaf(__builtin_amdgcn_cvt_f32_fp8((int)wd, 2), aj, out[w2 * 4 + 2]);
        out[w2 * 4 + 3] = fmaf(__builtin_amdgcn_cvt_f32_fp8((int)wd, 3), aj, out[w2 * 4 + 3]);
#else
#pragma unroll
        for (int c = 0; c < 4; ++c) {
          float v = fp8dec_sw((wd >> (8 * c)) & 0xffu);
          out[w2 * 4 + c] = fmaf(v, aj, out[w2 * 4 + c]);
        }
#endif
      }
    }
    __syncthreads();  // all alpha reads done before overwrite
#pragma unroll
    for (int k = 0; k < 8; ++k) {
      out[k] += __shfl_xor(out[k], 1, 64);
      out[k] += __shfl_xor(out[k], 2, 64);
      out[k] += __shfl_xor(out[k], 4, 64);
      out[k] += __shfl_xor(out[k], 8, 64);
    }
    if (m == 0) {
#pragma unroll
      for (int w2 = 0; w2 < 2; ++w2)
#pragma unroll
        for (int c = 0; c < 4; ++c)
          alpha[16 * (2 * h + w2) + 4 * g + c] =
              out[w2 * 4 + c] * 0.0078125f;  // keep stored = true*128
    }
    __syncthreads();
  }

  if (h == 0) {
    float sm = alpha[l] + alpha[l + 64];
    sm = wave_sum64(sm);
    const float C = (float)(log(128.0) + (double)TT * log((double)V));
    if (l == 0) ll[b] = __logf(sm) - C;
  }
}

// ---------------- fallback (round-3 path; E bf16 x128) --------------------
__global__ __launch_bounds__(256, 1)
void k_fwd_fb(const int* __restrict__ toks, const unsigned short* __restrict__ E128,
              const float* __restrict__ A2, const float* __restrict__ piZ,
              float* __restrict__ ll) {
  __shared__ float pb[2][KK];
  __shared__ float part[2 * KK];
  __shared__ int tk[TT];
  __shared__ float red[4];
  const int tid = threadIdx.x;
  const int j = tid & (KK - 1);
  const int h = tid >> 7;
  const int b = blockIdx.x;

  const int4* t4 = (const int4*)(toks + (size_t)b * TT);
  int4* l4 = (int4*)tk;
#pragma unroll
  for (int c = 0; c < TT / 4 / 256; ++c) l4[c * 256 + tid] = t4[c * 256 + tid];

  float Areg[64];
  {
    const float* Acol = A2 + (size_t)(h * 64) * KK + j;
#pragma unroll
    for (int i = 0; i < 64; ++i) Areg[i] = Acol[i * KK];
  }
  __syncthreads();

  const unsigned short* Ej = E128 + j;
  const float inv128 = 0.0078125f;
  float eA = inv128 * bflo((unsigned)Ej[(size_t)tk[1] * KK]);
  float eB = inv128 * bflo((unsigned)Ej[(size_t)tk[2] * KK]);
  float eC = inv128 * bflo((unsigned)Ej[(size_t)tk[3] * KK]);
  float eD = inv128 * bflo((unsigned)Ej[(size_t)tk[4] * KK]);
  if (h == 0) pb[0][j] = piZ[j] * inv128 * bflo((unsigned)Ej[(size_t)tk[0] * KK]);
  float Lacc = 0.f;
  __syncthreads();

  for (int t = 1; t < TT; ++t) {
    const float4* ph = (const float4*)&pb[(t - 1) & 1][h * 64];
    float a0 = 0.f, a1 = 0.f, a2 = 0.f, a3 = 0.f;
#pragma unroll
    for (int c = 0; c < 16; ++c) {
      float4 pv = ph[c];
      a0 = fmaf(pv.x, Areg[4 * c + 0], a0);
      a1 = fmaf(pv.y, Areg[4 * c + 1], a1);
      a2 = fmaf(pv.z, Areg[4 * c + 2], a2);
      a3 = fmaf(pv.w, Areg[4 * c + 3], a3);
    }
    part[2 * j + h] = (a0 + a1) + (a2 + a3);
    __syncthreads();

    float e = eA; eA = eB; eB = eC; eC = eD;
    int tn = tk[t + 4 < TT ? t + 4 : TT - 1];
    eD = inv128 * bflo((unsigned)Ej[(size_t)tn * KK]);

    float np = 0.f;
    if (h == 0) {
      float2 pr = *(const float2*)&part[2 * j];
      np = (pr.x + pr.y) * e;
    }
    if ((t & 63) == 0) {
      float v = wave_sum64(np);
      if ((tid & 63) == 0) red[tid >> 6] = v;
      __syncthreads();
      float tot = (red[0] + red[1]) + (red[2] + red[3]);
      np *= __builtin_amdgcn_rcpf(tot);
      if (tid == 0) Lacc += __logf(tot);
    } else if ((t & 3) == 0) {
      np *= 0x1p64f;
    }
    if (h == 0) pb[t & 1][j] = np;
    __syncthreads();
  }

  float lv = (h == 0) ? pb[(TT - 1) & 1][j] : 0.f;
  float v = wave_sum64(lv);
  if ((tid & 63) == 0) red[tid >> 6] = v;
  __syncthreads();
  float tot = (red[0] + red[1]) + (red[2] + red[3]);
  const float RESCALE_C = (float)(30720.0 * 0.6931471805599453);
  if (tid == 0) ll[b] = Lacc + __logf(tot) - RESCALE_C;
}

// ---------------- K5: final reduction ----------------
__global__ void k_final(const float* __restrict__ ll, float* __restrict__ out) {
  float v = ll[threadIdx.x];
  v = wave_sum64(v);
  if (threadIdx.x == 0) out[0] = -v;
}

extern "C" void kernel_launch(void* const* d_in, const int* in_sizes, int n_in,
                              void* d_out, int out_size, void* d_ws, size_t ws_size,
                              hipStream_t stream) {
  const int*   toks    = (const int*)d_in[0];
  const float* initlog = (const float*)d_in[1];
  const float* tag     = (const float*)d_in[2];
  const float* word    = (const float*)d_in[3];
  const float* bias    = (const float*)d_in[4];
  const float* q       = (const float*)d_in[5];
  const float* W       = (const float*)d_in[6];
  const float* tb      = (const float*)d_in[7];
  float* out = (float*)d_out;

  const int V = in_sizes[4];
  const int nPart = (V + 127) / 128;

  unsigned short* E128 = (unsigned short*)d_ws;        // V*128 bf16
  float* pZ      = (float*)(E128 + (size_t)V * KK);    // nPart*128
  float* A2      = pZ + (size_t)nPart * KK;            // 128^2 (fb)
  float* A2p     = A2 + KK * KK;                       // 128^2
  float* piZ     = A2p + KK * KK;                      // 128 (fb)
  float* piPlain = piZ + KK;                           // 128
  float* Zinv    = piPlain + KK;                       // 128
  float* ll      = Zinv + KK;                          // 64
  uintptr_t pp = (uintptr_t)(ll + BB);
  pp = (pp + 15) & ~(uintptr_t)15;
  uint4* P = (uint4*)pp;

  const size_t head = pp - (uintptr_t)d_ws;
  const size_t need48 = head + (size_t)48 * BB * 1024 * sizeof(uint4);  // 48MB P
  const size_t need32 = head + (size_t)32 * BB * 1024 * sizeof(uint4);  // 32MB P

  k_emis <<<nPart, 128, 0, stream>>>(tag, word, bias, E128, pZ, V);
  k_trans<<<KK, 128, 0, stream>>>(W, q, tb, pZ, initlog, A2, A2p, piZ,
                                  piPlain, Zinv, nPart, V);
  if (ws_size >= need48) {
    k_scan<48><<<48 * BB, 64, 0, stream>>>(toks, E128, A2p, Zinv, P);
    k_comb<<<BB, 256, 0, stream>>>(P, piPlain, E128, Zinv, toks, ll, V, 48);
  } else if (ws_size >= need32) {
    k_scan<32><<<32 * BB, 64, 0, stream>>>(toks, E128, A2p, Zinv, P);
    k_comb<<<BB, 256, 0, stream>>>(P, piPlain, E128, Zinv, toks, ll, V, 32);
  } else {
    k_fwd_fb<<<BB, 256, 0, stream>>>(toks, E128, A2, piZ, ll);
  }
  k_final<<<1, BB, 0, stream>>>(ll, out);
}

// Round 12
// 374.267 us; speedup vs baseline: 8.5464x; 4.3771x over previous
//
#include <hip/hip_runtime.h>

// Neural HMM forward-algorithm NLL.  K=128, V=50257, D=H=128, B=64, T=2048.
//
// Associative scan over t: alpha_t = alpha_{t-1} M_t  (M_t = A diag(e_t)).
// 32 segments x 64 batches = 2048 chains, each propagating a 128x128 matrix
// Q <- diag(e_t) A^T Q via MX-FP8 MFMA (mfma_scale 16x16x128).
//
// Evidence ledger: r9 = (64,2), NSEG=32, fat epilogue: 246us, MfmaUtil 46%,
// VALUBusy 68% -> VALU-issue-bound. r10 = lean epilogue BUT (64,4): reg cap
// 128 < live ~215 -> spill catastrophe. r11 = (64,3): cap 170 still < 215 ->
// spill. 2 waves/SIMD is the register-feasible ceiling. This round: r10's
// lean step body (hoisted e-expansion + pk-mul) at r9's proven (64,2).
//
//  K1 k_emis : E128[v][k] = bf16(128*exp(tag_k . word_v + bias_v)) + partial Z
//  K2 k_trans: A2 (Z-folded, fb), A2p = 128*softmax rows, piZ (fb),
//              piPlain = softmax(init), Zinv[j] = V/Z_j
//  K3 k_scan<NS> : per chain: Q init I*128 (fp8), ~2047/NS steps of
//              Qstored <- 128 * diag(E*V/Z) A^T Qtrue (stored = true*128;
//              SA=SB=2^-7 cancel the two x128 of the operands).
//  K4 k_comb : per batch, 4 waves: alpha <- Q_s alpha (s ascending),
//              HW v_cvt_f32_fp8 decode, x2^-7 per segment.
//              LL_b = log(sum/128) - T*log(V).
//  K5 k_final: out = -sum_b ll[b]

#define KK 128
#define TT 2048
#define BB 64

typedef int v8i __attribute__((ext_vector_type(8)));
typedef float v4f __attribute__((ext_vector_type(4)));

__device__ __forceinline__ float wave_sum64(float v) {
#pragma unroll
  for (int m = 32; m; m >>= 1) v += __shfl_xor(v, m, 64);
  return v;
}
__device__ __forceinline__ float wave_max64(float v) {
#pragma unroll
  for (int m = 32; m; m >>= 1) v = fmaxf(v, __shfl_xor(v, m, 64));
  return v;
}
// f32 -> bf16 round-to-nearest-even (positive normals here)
__device__ __forceinline__ unsigned short f2bf(float x) {
  union { float f; unsigned u; } c; c.f = x;
  unsigned r = c.u + 0x7fffu + ((c.u >> 16) & 1u);
  return (unsigned short)(r >> 16);
}
__device__ __forceinline__ float bflo(unsigned u) {
  union { unsigned u; float f; } c; c.u = u << 16; return c.f;
}
__device__ __forceinline__ float bfhi(unsigned u) {
  union { unsigned u; float f; } c; c.u = u & 0xffff0000u; return c.f;
}

// fp8 e4m3fn byte -> f32 (ALU fallback; positive data)
__device__ __forceinline__ float fp8dec_sw(unsigned byte) {
  unsigned em = byte & 0x7fu;
  float v;
  if (em < 8) {
    v = (float)em * 0x1p-9f;
  } else {
    union { unsigned u; float f; } x;
    x.u = (em << 20) + (120u << 23);
    v = x.f;
  }
  return (byte & 0x80u) ? -v : v;
}

// ---------------- K1: emission table E128 (V x K, bf16 of 128*e) ----------
__global__ __launch_bounds__(128, 1)
void k_emis(const float* __restrict__ tag, const float* __restrict__ word,
            const float* __restrict__ bias, unsigned short* __restrict__ E128,
            float* __restrict__ partialZ, int V) {
  __shared__ float4 wtile[128 * 32];
  __shared__ float btile[128];
  const int tid = threadIdx.x;
  const int v0 = blockIdx.x * 128;

  const float4* w4 = (const float4*)word;
  const int maxi = V * 32 - 1;
#pragma unroll
  for (int it = 0; it < 32; ++it) {
    int idx = it * 128 + tid;
    int g = v0 * 32 + idx;
    wtile[idx] = w4[min(g, maxi)];
  }
  btile[tid] = (v0 + tid < V) ? bias[v0 + tid] : 0.f;

  float treg[128];
  const float4* t4 = (const float4*)(tag + (size_t)tid * 128);
#pragma unroll
  for (int c = 0; c < 32; ++c) {
    float4 x = t4[c];
    treg[4 * c + 0] = x.x; treg[4 * c + 1] = x.y;
    treg[4 * c + 2] = x.z; treg[4 * c + 3] = x.w;
  }
  __syncthreads();

  float zp = 0.f;
  for (int v = 0; v < 128; ++v) {
    if (v0 + v >= V) break;  // uniform
    const float4* row = &wtile[v * 32];
    float a0 = 0.f, a1 = 0.f, a2 = 0.f, a3 = 0.f;
#pragma unroll
    for (int c = 0; c < 32; ++c) {
      float4 pv = row[c];
      a0 = fmaf(pv.x, treg[4 * c + 0], a0);
      a1 = fmaf(pv.y, treg[4 * c + 1], a1);
      a2 = fmaf(pv.z, treg[4 * c + 2], a2);
      a3 = fmaf(pv.w, treg[4 * c + 3], a3);
    }
    float e = __expf((a0 + a1) + (a2 + a3) + btile[v]);
    E128[(size_t)(v0 + v) * KK + tid] = f2bf(128.f * e);
    zp += e;
  }
  partialZ[(size_t)blockIdx.x * KK + tid] = zp;
}

// ---------------- K2: transition matrix + piZ/piPlain/Zinv/A2p ------------
__global__ __launch_bounds__(128)
void k_trans(const float* __restrict__ W, const float* __restrict__ q,
             const float* __restrict__ tb, const float* __restrict__ pZ,
             const float* __restrict__ initlog, float* __restrict__ A2,
             float* __restrict__ A2p, float* __restrict__ piZ,
             float* __restrict__ piPlain, float* __restrict__ Zinv,
             int nPart, int V) {
  __shared__ float qs[KK];
  __shared__ float r0[2], r1[2];
  const int j = threadIdx.x, i = blockIdx.x;
  qs[j] = q[j];
  __syncthreads();

  const float4* w4 = (const float4*)(W + ((size_t)(i * KK + j)) * KK);
  const float4* q4 = (const float4*)qs;
  float a0 = 0.f, a1 = 0.f, a2 = 0.f, a3 = 0.f;
#pragma unroll
  for (int c = 0; c < KK / 4; ++c) {
    float4 wv = w4[c], qv = q4[c];
    a0 = fmaf(wv.x, qv.x, a0); a1 = fmaf(wv.y, qv.y, a1);
    a2 = fmaf(wv.z, qv.z, a2); a3 = fmaf(wv.w, qv.w, a3);
  }
  float logit = (a0 + a1) + (a2 + a3) + tb[i * KK + j];

  float m = wave_max64(logit);
  if ((j & 63) == 0) r0[j >> 6] = m;
  __syncthreads();
  m = fmaxf(r0[0], r0[1]);
  float e = __expf(logit - m);
  float s = wave_sum64(e);
  if ((j & 63) == 0) r1[j >> 6] = s;
  __syncthreads();
  s = r1[0] + r1[1];

  float Z0 = 0.f, Z1 = 0.f, Z2 = 0.f, Z3 = 0.f;
  float Z4 = 0.f, Z5 = 0.f, Z6 = 0.f, Z7 = 0.f;
  int p = 0;
  for (; p + 8 <= nPart; p += 8) {
    Z0 += pZ[(size_t)(p + 0) * KK + j]; Z1 += pZ[(size_t)(p + 1) * KK + j];
    Z2 += pZ[(size_t)(p + 2) * KK + j]; Z3 += pZ[(size_t)(p + 3) * KK + j];
    Z4 += pZ[(size_t)(p + 4) * KK + j]; Z5 += pZ[(size_t)(p + 5) * KK + j];
    Z6 += pZ[(size_t)(p + 6) * KK + j]; Z7 += pZ[(size_t)(p + 7) * KK + j];
  }
  for (; p < nPart; ++p) Z0 += pZ[(size_t)p * KK + j];
  float Z = ((Z0 + Z1) + (Z2 + Z3)) + ((Z4 + Z5) + (Z6 + Z7));

  A2[i * KK + j] = e / (s * Z);        // fallback path (Z-folded)
  A2p[i * KK + j] = 128.0f * e / s;    // scan path: pure softmax x128 (~1.0)

  if (i == 0) {
    float x = initlog[j];
    __syncthreads();
    float m2 = wave_max64(x);
    if ((j & 63) == 0) r0[j >> 6] = m2;
    __syncthreads();
    m2 = fmaxf(r0[0], r0[1]);
    float e2 = __expf(x - m2);
    float s2 = wave_sum64(e2);
    if ((j & 63) == 0) r1[j >> 6] = s2;
    __syncthreads();
    s2 = r1[0] + r1[1];
    piZ[j] = e2 / (s2 * Z);
    piPlain[j] = e2 / s2;
    Zinv[j] = (float)V / Z;
  }
}

// ---------------- K3: segmented matrix scan (MX-FP8) ----------------------
// NS*64 blocks x 64 thr (1 wave). chain = s*64+b. lane: m = l&15, g = l>>4.
//   af[it] word w byte c : A2p[16w+4g+c][16it+m] * Zinv[16it+m]   (A-operand)
//   Q[jt]  word w byte c : Qstored[row 16w+4g+c][col 16jt+m]      (B-operand)
//   D(it,jt) lane reg r  -> row 16it+4g+r, col 16jt+m  -> Q[jt] word it.
// Step: Qstored <- 128*( diag(E*zi) A^T Qtrue );  SA=SB=2^-7.
// Lean epilogue (r10 body): e expanded ONCE per step (32 ops, not 256),
// pk-mul via v4f*v4f. Occupancy: (64,2) — the register-feasible ceiling
// (live set ~215 regs; 3-wave cap 170 spills, measured r10/r11).
__device__ __forceinline__ void scan_step(
    int n, int nst, const int* __restrict__ tks,
    const unsigned short* __restrict__ E128, const v8i (&af)[8], v8i (&Q)[8],
    uint2 (&evU)[8], uint2 (&evL)[8], int g) {
  // expand current e-row (evU) to f32 once per step
  v4f ev4[8];
#pragma unroll
  for (int it = 0; it < 8; ++it) {
    ev4[it][0] = bflo(evU[it].x); ev4[it][1] = bfhi(evU[it].x);
    ev4[it][2] = bflo(evU[it].y); ev4[it][3] = bfhi(evU[it].y);
  }
  // prefetch next step's e-row (consumed one full step later)
  int np = (n + 1 < nst) ? n + 1 : nst - 1;
  const unsigned short* ern = E128 + (size_t)tks[np] * KK;
#pragma unroll
  for (int it = 0; it < 8; ++it)
    evL[it] = *(const uint2*)(ern + 16 * it + 4 * g);

  const v4f ZED = {0.f, 0.f, 0.f, 0.f};
#pragma unroll
  for (int jt = 0; jt < 8; ++jt) {
    v4f acc[8];
#pragma unroll
    for (int it = 0; it < 8; ++it)
      acc[it] = __builtin_amdgcn_mfma_scale_f32_16x16x128_f8f6f4(
          af[it], Q[jt], ZED, 0, 0, 0, 0x78787878, 0, 0x78787878);
#pragma unroll
    for (int it = 0; it < 8; ++it) {
      v4f nn = acc[it] * ev4[it];  // v_pk_mul_f32 x2
      int w = __builtin_amdgcn_cvt_pk_fp8_f32(nn[0], nn[1], 0, false);
      w = __builtin_amdgcn_cvt_pk_fp8_f32(nn[2], nn[3], w, true);
      Q[jt][it] = w;
    }
  }
}

template <int NS>
__global__ __launch_bounds__(64, 2)
void k_scan(const int* __restrict__ toks, const unsigned short* __restrict__ E128,
            const float* __restrict__ A2p, const float* __restrict__ Zinv,
            uint4* __restrict__ P) {
  __shared__ int tks[64];  // max segment length
  const int chain = blockIdx.x;
  const int s = chain >> 6;
  const int b = chain & 63;
  const int l = threadIdx.x, m = l & 15, g = l >> 4;
  // segments tile t = 1..2047 (2047 steps), uneven lengths allowed
  const int t0 = 1 + (2047 * s) / NS;
  const int nst = (2047 * (s + 1)) / NS - (2047 * s) / NS;
  if (l < nst) tks[l] = toks[(size_t)b * TT + t0 + l];

  // static A-operand: A2p with Zinv folded into output columns
  v8i af[8];
#pragma unroll
  for (int it = 0; it < 8; ++it) {
    const int colj = 16 * it + m;
    const float zj = Zinv[colj];
#pragma unroll
    for (int w = 0; w < 8; ++w) {
      const float* ap = A2p + (size_t)(16 * w + 4 * g) * KK + colj;
      int ww = __builtin_amdgcn_cvt_pk_fp8_f32(ap[0] * zj, ap[KK] * zj, 0, false);
      ww = __builtin_amdgcn_cvt_pk_fp8_f32(ap[2 * KK] * zj, ap[3 * KK] * zj, ww, true);
      af[it][w] = ww;
    }
  }

  // Q = 128 * Identity (fp8 0x70 = 128.0 at row==col)
  v8i Q[8];
  const unsigned diag = (g == (m >> 2)) ? (0x70u << (8 * (m & 3))) : 0u;
#pragma unroll
  for (int jt = 0; jt < 8; ++jt) {
#pragma unroll
    for (int w = 0; w < 8; ++w) Q[jt][w] = (w == jt) ? (int)diag : 0;
  }

  __syncthreads();

  uint2 evA[8], evB[8];
  {
    const unsigned short* er0 = E128 + (size_t)tks[0] * KK;
#pragma unroll
    for (int it = 0; it < 8; ++it) evA[it] = *(const uint2*)(er0 + 16 * it + 4 * g);
  }
  const int pairs = nst >> 1;
  for (int c = 0; c < pairs; ++c) {
    scan_step(2 * c + 0, nst, tks, E128, af, Q, evA, evB, g);
    scan_step(2 * c + 1, nst, tks, E128, af, Q, evB, evA, g);
  }
  if (nst & 1) scan_step(nst - 1, nst, tks, E128, af, Q, evA, evB, g);

  // dump Q (per-lane natural order; combine uses the same indexing)
  uint4* base = P + (size_t)chain * 1024;
#pragma unroll
  for (int jt = 0; jt < 8; ++jt) {
    union { v8i v; uint4 u[2]; } x; x.v = Q[jt];
    base[jt * 128 + l * 2 + 0] = x.u[0];
    base[jt * 128 + l * 2 + 1] = x.u[1];
  }
}

// ---------------- K4: combine segments per batch (4 waves) ----------------
// alpha^T <- Q_s alpha^T, s ascending. 256 thr: wave h handles word-pairs
// w in {2h, 2h+1} (rows [32h, 32h+32)). Lane (m,g): cols {16jt+m}, its bytes
// rows {16w+4g+c}; reduce partial row-sums over the 16 m-lanes, 2 barriers/s.
// fp8 decode via HW v_cvt_f32_fp8 (no LDS LUT).
__global__ __launch_bounds__(256, 1)
void k_comb(const uint4* __restrict__ P, const float* __restrict__ piPlain,
            const unsigned short* __restrict__ E128, const float* __restrict__ Zinv,
            const int* __restrict__ toks, float* __restrict__ ll, int V,
            int nseg) {
  __shared__ float alpha[KK];
  const int b = blockIdx.x;
  const int tid = threadIdx.x;
  const int h = tid >> 6;
  const int l = tid & 63, m = l & 15, g = l >> 4;

  if (tid < KK) {  // alpha_1 = pi * E*zi (stored = true*128 via E128's x128)
    int tok0 = toks[(size_t)b * TT];
    alpha[tid] = piPlain[tid] * bflo((unsigned)E128[(size_t)tok0 * KK + tid]) *
                 Zinv[tid];
  }
  __syncthreads();

  const unsigned* P32 = (const unsigned*)P;
  for (int s = 0; s < nseg; ++s) {
    const size_t cbase = ((size_t)(s * 64 + b)) * 4096;
    float ac[8];
#pragma unroll
    for (int jt = 0; jt < 8; ++jt) ac[jt] = alpha[16 * jt + m];
    float out[8];  // [w2][c]
#pragma unroll
    for (int k = 0; k < 8; ++k) out[k] = 0.f;
#pragma unroll
    for (int jt = 0; jt < 8; ++jt) {
      const float aj = ac[jt];
#pragma unroll
      for (int w2 = 0; w2 < 2; ++w2) {
        unsigned wd = P32[cbase + jt * 512 + l * 8 + (2 * h + w2)];
#if __has_builtin(__builtin_amdgcn_cvt_f32_fp8)
        out[w2 * 4 + 0] = fmaf(__builtin_amdgcn_cvt_f32_fp8((int)wd, 0), aj, out[w2 * 4 + 0]);
        out[w2 * 4 + 1] = fmaf(__builtin_amdgcn_cvt_f32_fp8((int)wd, 1), aj, out[w2 * 4 + 1]);
        out[w2 * 4 + 2] = fmaf(__builtin_amdgcn_cvt_f32_fp8((int)wd, 2), aj, out[w2 * 4 + 2]);
        out[w2 * 4 + 3] = fmaf(__builtin_amdgcn_cvt_f32_fp8((int)wd, 3), aj, out[w2 * 4 + 3]);
#else
#pragma unroll
        for (int c = 0; c < 4; ++c) {
          float v = fp8dec_sw((wd >> (8 * c)) & 0xffu);
          out[w2 * 4 + c] = fmaf(v, aj, out[w2 * 4 + c]);
        }
#endif
      }
    }
    __syncthreads();  // all alpha reads done before overwrite
#pragma unroll
    for (int k = 0; k < 8; ++k) {
      out[k] += __shfl_xor(out[k], 1, 64);
      out[k] += __shfl_xor(out[k], 2, 64);
      out[k] += __shfl_xor(out[k], 4, 64);
      out[k] += __shfl_xor(out[k], 8, 64);
    }
    if (m == 0) {
#pragma unroll
      for (int w2 = 0; w2 < 2; ++w2)
#pragma unroll
        for (int c = 0; c < 4; ++c)
          alpha[16 * (2 * h + w2) + 4 * g + c] =
              out[w2 * 4 + c] * 0.0078125f;  // keep stored = true*128
    }
    __syncthreads();
  }

  if (h == 0) {
    float sm = alpha[l] + alpha[l + 64];
    sm = wave_sum64(sm);
    const float C = (float)(log(128.0) + (double)TT * log((double)V));
    if (l == 0) ll[b] = __logf(sm) - C;
  }
}

// ---------------- fallback (round-3 path; E bf16 x128) --------------------
__global__ __launch_bounds__(256, 1)
void k_fwd_fb(const int* __restrict__ toks, const unsigned short* __restrict__ E128,
              const float* __restrict__ A2, const float* __restrict__ piZ,
              float* __restrict__ ll) {
  __shared__ float pb[2][KK];
  __shared__ float part[2 * KK];
  __shared__ int tk[TT];
  __shared__ float red[4];
  const int tid = threadIdx.x;
  const int j = tid & (KK - 1);
  const int h = tid >> 7;
  const int b = blockIdx.x;

  const int4* t4 = (const int4*)(toks + (size_t)b * TT);
  int4* l4 = (int4*)tk;
#pragma unroll
  for (int c = 0; c < TT / 4 / 256; ++c) l4[c * 256 + tid] = t4[c * 256 + tid];

  float Areg[64];
  {
    const float* Acol = A2 + (size_t)(h * 64) * KK + j;
#pragma unroll
    for (int i = 0; i < 64; ++i) Areg[i] = Acol[i * KK];
  }
  __syncthreads();

  const unsigned short* Ej = E128 + j;
  const float inv128 = 0.0078125f;
  float eA = inv128 * bflo((unsigned)Ej[(size_t)tk[1] * KK]);
  float eB = inv128 * bflo((unsigned)Ej[(size_t)tk[2] * KK]);
  float eC = inv128 * bflo((unsigned)Ej[(size_t)tk[3] * KK]);
  float eD = inv128 * bflo((unsigned)Ej[(size_t)tk[4] * KK]);
  if (h == 0) pb[0][j] = piZ[j] * inv128 * bflo((unsigned)Ej[(size_t)tk[0] * KK]);
  float Lacc = 0.f;
  __syncthreads();

  for (int t = 1; t < TT; ++t) {
    const float4* ph = (const float4*)&pb[(t - 1) & 1][h * 64];
    float a0 = 0.f, a1 = 0.f, a2 = 0.f, a3 = 0.f;
#pragma unroll
    for (int c = 0; c < 16; ++c) {
      float4 pv = ph[c];
      a0 = fmaf(pv.x, Areg[4 * c + 0], a0);
      a1 = fmaf(pv.y, Areg[4 * c + 1], a1);
      a2 = fmaf(pv.z, Areg[4 * c + 2], a2);
      a3 = fmaf(pv.w, Areg[4 * c + 3], a3);
    }
    part[2 * j + h] = (a0 + a1) + (a2 + a3);
    __syncthreads();

    float e = eA; eA = eB; eB = eC; eC = eD;
    int tn = tk[t + 4 < TT ? t + 4 : TT - 1];
    eD = inv128 * bflo((unsigned)Ej[(size_t)tn * KK]);

    float np = 0.f;
    if (h == 0) {
      float2 pr = *(const float2*)&part[2 * j];
      np = (pr.x + pr.y) * e;
    }
    if ((t & 63) == 0) {
      float v = wave_sum64(np);
      if ((tid & 63) == 0) red[tid >> 6] = v;
      __syncthreads();
      float tot = (red[0] + red[1]) + (red[2] + red[3]);
      np *= __builtin_amdgcn_rcpf(tot);
      if (tid == 0) Lacc += __logf(tot);
    } else if ((t & 3) == 0) {
      np *= 0x1p64f;
    }
    if (h == 0) pb[t & 1][j] = np;
    __syncthreads();
  }

  float lv = (h == 0) ? pb[(TT - 1) & 1][j] : 0.f;
  float v = wave_sum64(lv);
  if ((tid & 63) == 0) red[tid >> 6] = v;
  __syncthreads();
  float tot = (red[0] + red[1]) + (red[2] + red[3]);
  const float RESCALE_C = (float)(30720.0 * 0.6931471805599453);
  if (tid == 0) ll[b] = Lacc + __logf(tot) - RESCALE_C;
}

// ---------------- K5: final reduction ----------------
__global__ void k_final(const float* __restrict__ ll, float* __restrict__ out) {
  float v = ll[threadIdx.x];
  v = wave_sum64(v);
  if (threadIdx.x == 0) out[0] = -v;
}

extern "C" void kernel_launch(void* const* d_in, const int* in_sizes, int n_in,
                              void* d_out, int out_size, void* d_ws, size_t ws_size,
                              hipStream_t stream) {
  const int*   toks    = (const int*)d_in[0];
  const float* initlog = (const float*)d_in[1];
  const float* tag     = (const float*)d_in[2];
  const float* word    = (const float*)d_in[3];
  const float* bias    = (const float*)d_in[4];
  const float* q       = (const float*)d_in[5];
  const float* W       = (const float*)d_in[6];
  const float* tb      = (const float*)d_in[7];
  float* out = (float*)d_out;

  const int V = in_sizes[4];
  const int nPart = (V + 127) / 128;

  unsigned short* E128 = (unsigned short*)d_ws;        // V*128 bf16
  float* pZ      = (float*)(E128 + (size_t)V * KK);    // nPart*128
  float* A2      = pZ + (size_t)nPart * KK;            // 128^2 (fb)
  float* A2p     = A2 + KK * KK;                       // 128^2
  float* piZ     = A2p + KK * KK;                      // 128 (fb)
  float* piPlain = piZ + KK;                           // 128
  float* Zinv    = piPlain + KK;                       // 128
  float* ll      = Zinv + KK;                          // 64
  uintptr_t pp = (uintptr_t)(ll + BB);
  pp = (pp + 15) & ~(uintptr_t)15;
  uint4* P = (uint4*)pp;

  const size_t head = pp - (uintptr_t)d_ws;
  const size_t need32 = head + (size_t)32 * BB * 1024 * sizeof(uint4);  // 32MB P

  k_emis <<<nPart, 128, 0, stream>>>(tag, word, bias, E128, pZ, V);
  k_trans<<<KK, 128, 0, stream>>>(W, q, tb, pZ, initlog, A2, A2p, piZ,
                                  piPlain, Zinv, nPart, V);
  if (ws_size >= need32) {
    k_scan<32><<<32 * BB, 64, 0, stream>>>(toks, E128, A2p, Zinv, P);
    k_comb<<<BB, 256, 0, stream>>>(P, piPlain, E128, Zinv, toks, ll, V, 32);
  } else {
    k_fwd_fb<<<BB, 256, 0, stream>>>(toks, E128, A2, piZ, ll);
  }
  k_final<<<1, BB, 0, stream>>>(ll, out);
}